// Round 8
// baseline (519.819 us; speedup 1.0000x reference)
//
#include <hip/hip_runtime.h>
#include <math.h>

namespace {

constexpr int   kB     = 16;
constexpr int   kA     = 65536;
constexpr int   kM     = 32;
constexpr int   kC     = 20;
constexpr float kImg   = 600.0f;
constexpr int   kBlock = 256;

// stream geometry
constexpr int kSBlocks       = 2048;
constexpr int kStreamThreads = kSBlocks * kBlock;          // 524,288
constexpr int kTotalF4       = kB * kA * kC / 4;           // 5,242,880
constexpr int kF4PerThread   = kTotalF4 / kStreamThreads;  // 10 (exact)

// anchor geometry: 1 anchor/thread, 2D grid (256, 16)
constexpr int kGridX = kA / kBlock;                        // 256

// fix geometry
constexpr int kFBlocks = 128;

// workspace layout (ws is >300 MB, poisoned every iter by the harness fill)
constexpr int kNPartial = kSBlocks + kFBlocks;             // 2176 slots x 3 floats
constexpr int kCntPos   = 3 * kNPartial;                   // u32 index 6528
constexpr int kCntIgn   = kCntPos + 1;                     // u32 index 6529
constexpr int kPosBase  = 8192;                            // u32 index; cap > 1M
constexpr int kIgnBase  = kPosBase + (1 << 20) + 65536;    // 1,122,304; cap > 1M

__device__ __forceinline__ float smooth_l1(float d) {
    float ad = fabsf(d);
    return ad < 1.0f ? 0.5f * d * d : ad - 0.5f;
}

// f0(x) = sigmoid(x)^2 * softplus(x)  (t=0 focal term; t=1 is f0(-x)).
// Single definition shared by stream and corrections -> exact cancellation.
__device__ __forceinline__ float f0s(float x) {
    float u  = __expf(-x);
    float d  = 1.0f + u;
    float s  = __builtin_amdgcn_rcpf(d);       // sigmoid(x)
    float sp = x + __logf(d);                  // softplus(x)
    return s * s * sp;
}

// Lessons ledger:
//  R2: no launch_bounds min-waves arg (",6" -> VGPR cap 40 -> 359 MB spill).
//  R4: role-split INSIDE one kernel fails (shared regalloc -> VGPR-128 cliff).
//  R5/R6: VALU cuts in the fused kernel were neutral (structure-bound).
//  R7: decomposition: anchor kernel = 55us of the 75; its exec-masked pos/ign
//      bodies run in ~every wave (1-(1-p)^64) with scattered 80B loads and
//      push VGPR to 128. This round: compact pos/ign indices (1 atomic/wave),
//      process them in a tiny retina_fix kernel; anchor becomes pure VALU.

// ---- Kernel 1: target-free focal stream over cls_preds + counter zeroing ---
__global__ __launch_bounds__(kBlock) void retina_stream(
    const float* __restrict__ cls_preds,
    float* __restrict__ partial,           // slots [0, kSBlocks)
    unsigned int* __restrict__ wsu)
{
    __shared__ float sred[kBlock / 64];

    if (blockIdx.x == 0 && threadIdx.x == 0) {
        wsu[kCntPos] = 0u;                 // anchor kernel runs strictly after
        wsu[kCntIgn] = 0u;
    }

    const float4* cp = (const float4*)cls_preds;
    const int t0 = blockIdx.x * kBlock + threadIdx.x;

    float csum = 0.0f;
#pragma unroll
    for (int i = 0; i < kF4PerThread; ++i) {
        float4 v = cp[t0 + i * kStreamThreads];   // coalesced 1 KiB/instr/wave
        csum += f0s(v.x) + f0s(v.y) + f0s(v.z) + f0s(v.w);
    }

#pragma unroll
    for (int off = 32; off > 0; off >>= 1)
        csum += __shfl_down(csum, off);
    const int lane = threadIdx.x & 63;
    const int wid  = threadIdx.x >> 6;
    if (lane == 0) sred[wid] = csum;
    __syncthreads();
    if (threadIdx.x == 0) {
        float c = 0.0f;
#pragma unroll
        for (int i = 0; i < kBlock / 64; ++i) c += sred[i];
        partial[3 * blockIdx.x + 0] = 0.0f;
        partial[3 * blockIdx.x + 1] = 0.75f * c;
        partial[3 * blockIdx.x + 2] = 0.0f;
    }
}

// ---- Kernel 2: IoU argmax + classification + wave-compacted index lists ----
__global__ __launch_bounds__(kBlock) void retina_anchor(
    const float* __restrict__ iou_boxes,   // [A, 4] xywh
    const float* __restrict__ targets,     // [B*M, 6]
    unsigned int* __restrict__ wsu)
{
    __shared__ float4 sbox[kM];    // x1, y1, x2+1, y2+1 (pixels)
    __shared__ float  sarea[kM];   // target area (+1 convention)

    const int b = blockIdx.y;
    const int a = blockIdx.x * kBlock + threadIdx.x;

    if (threadIdx.x < kM) {
        const float* t = targets + ((size_t)(b * kM + threadIdx.x)) * 6;
        float cx = t[2] * kImg, cy = t[3] * kImg;
        float w  = t[4] * kImg, h  = t[5] * kImg;
        float x1  = cx - w * 0.5f,        y1  = cy - h * 0.5f;
        float x2p = cx + w * 0.5f + 1.0f, y2p = cy + h * 0.5f + 1.0f;
        sbox[threadIdx.x]  = make_float4(x1, y1, x2p, y2p);
        sarea[threadIdx.x] = (x2p - x1) * (y2p - y1);
    }

    const float4 an = *(const float4*)(iou_boxes + (size_t)a * 4);

    __syncthreads();

    const float ax1  = an.x - an.z * 0.5f;
    const float ay1  = an.y - an.w * 0.5f;
    const float ax2p = an.x + an.z * 0.5f + 1.0f;
    const float ay2p = an.y + an.w * 0.5f + 1.0f;
    const float aarea = (ax2p - ax1) * (ay2p - ay1);

    float best = -1.0f;
    int   mid  = 0;
#pragma unroll
    for (int m = 0; m < kM; ++m) {
        float4 q = sbox[m];
        float lx = fmaxf(ax1,  q.x);
        float ly = fmaxf(ay1,  q.y);
        float rx = fminf(ax2p, q.z);
        float ry = fminf(ay2p, q.w);
        float w  = fmaxf(rx - lx, 0.0f);
        float h  = fmaxf(ry - ly, 0.0f);
        float inter = w * h;
        float uni   = aarea + sarea[m] - inter;
        float iou   = inter * __builtin_amdgcn_rcpf(uni);
        if (iou > best) { best = iou; mid = m; }
    }

    const bool pos = best >= 0.5f;
    const bool ign = (best > 0.4f) && !pos;
    const int  lane = threadIdx.x & 63;
    const unsigned g = (unsigned)(b * kA + a);            // < 2^20

    // pos list: packed (g<<5)|mid
    unsigned long long pm = __ballot(pos);
    if (pm) {
        int base = 0;
        if (lane == 0) base = (int)atomicAdd(wsu + kCntPos, (unsigned)__popcll(pm));
        base = __builtin_amdgcn_readfirstlane(base);
        if (pos) {
            unsigned off = (unsigned)__popcll(pm & ((1ull << lane) - 1ull));
            wsu[kPosBase + (unsigned)base + off] = (g << 5) | (unsigned)mid;
        }
    }
    // ign list: g
    unsigned long long im = __ballot(ign);
    if (im) {
        int base = 0;
        if (lane == 0) base = (int)atomicAdd(wsu + kCntIgn, (unsigned)__popcll(im));
        base = __builtin_amdgcn_readfirstlane(base);
        if (ign) {
            unsigned off = (unsigned)__popcll(im & ((1ull << lane) - 1ull));
            wsu[kIgnBase + (unsigned)base + off] = g;
        }
    }
}

// ---- Kernel 3: process compacted pos/ign lists (loc loss + corrections) ----
__global__ __launch_bounds__(kBlock) void retina_fix(
    const float* __restrict__ loc_preds,
    const float* __restrict__ cls_preds,
    const float* __restrict__ iou_boxes,
    const float* __restrict__ targets,
    const unsigned int* __restrict__ wsu,
    float* __restrict__ partial)           // slots [kSBlocks, kSBlocks+kFBlocks)
{
    __shared__ float sred[2][kBlock / 64];

    const unsigned npos = wsu[kCntPos];
    const unsigned nign = wsu[kCntIgn];

    float loc_sum = 0.0f, cls_sum = 0.0f;

    for (unsigned i = blockIdx.x * kBlock + threadIdx.x; i < npos;
         i += kFBlocks * kBlock) {
        const unsigned e = wsu[kPosBase + i];
        const unsigned g = e >> 5;
        const int mid = (int)(e & 31u);
        const int b = (int)(g >> 16);
        const int a = (int)(g & 65535u);
        const float4 an = *(const float4*)(iou_boxes + (size_t)a * 4);
        const float* t = targets + ((size_t)(b * kM + mid)) * 6;
        const float cx = t[2] * kImg, cy = t[3] * kImg;
        const float w  = t[4] * kImg, h  = t[5] * kImg;
        const float4 lp = *(const float4*)(loc_preds + (size_t)g * 4);
        float ltx = (cx - an.x) * __builtin_amdgcn_rcpf(an.z);
        float lty = (cy - an.y) * __builtin_amdgcn_rcpf(an.w);
        float ltw = __logf(w * __builtin_amdgcn_rcpf(an.z));
        float lth = __logf(h * __builtin_amdgcn_rcpf(an.w));
        loc_sum += smooth_l1(lp.x - ltx) + smooth_l1(lp.y - lty) +
                   smooth_l1(lp.z - ltw) + smooth_l1(lp.w - lth);
        const int label = (int)t[1];
        const float x = cls_preds[(size_t)g * kC + label];
        cls_sum += 0.25f * f0s(-x) - 0.75f * f0s(x);
    }

    for (unsigned i = blockIdx.x * kBlock + threadIdx.x; i < nign;
         i += kFBlocks * kBlock) {
        const unsigned g = wsu[kIgnBase + i];
        const float* rp = cls_preds + (size_t)g * kC;
        const float4 r0 = *(const float4*)(rp + 0);
        const float4 r1 = *(const float4*)(rp + 4);
        const float4 r2 = *(const float4*)(rp + 8);
        const float4 r3 = *(const float4*)(rp + 12);
        const float4 r4 = *(const float4*)(rp + 16);
        float s =
            f0s(r0.x) + f0s(r0.y) + f0s(r0.z) + f0s(r0.w) +
            f0s(r1.x) + f0s(r1.y) + f0s(r1.z) + f0s(r1.w) +
            f0s(r2.x) + f0s(r2.y) + f0s(r2.z) + f0s(r2.w) +
            f0s(r3.x) + f0s(r3.y) + f0s(r3.z) + f0s(r3.w) +
            f0s(r4.x) + f0s(r4.y) + f0s(r4.z) + f0s(r4.w);
        cls_sum -= 0.75f * s;
    }

#pragma unroll
    for (int off = 32; off > 0; off >>= 1) {
        loc_sum += __shfl_down(loc_sum, off);
        cls_sum += __shfl_down(cls_sum, off);
    }
    const int lane = threadIdx.x & 63;
    const int wid  = threadIdx.x >> 6;
    if (lane == 0) { sred[0][wid] = loc_sum; sred[1][wid] = cls_sum; }
    __syncthreads();
    if (threadIdx.x == 0) {
        float l = 0.0f, c = 0.0f;
#pragma unroll
        for (int i = 0; i < kBlock / 64; ++i) { l += sred[0][i]; c += sred[1][i]; }
        const int slot = kSBlocks + blockIdx.x;
        partial[3 * slot + 0] = l;
        partial[3 * slot + 1] = c;
        partial[3 * slot + 2] = (blockIdx.x == 0) ? (float)npos : 0.0f;
    }
}

__global__ __launch_bounds__(1024) void retina_final(
    const float* __restrict__ partial, float* __restrict__ out)
{
    __shared__ float s[3][16];
    float l = 0.0f, c = 0.0f, n = 0.0f;
    for (int i = threadIdx.x; i < kNPartial; i += 1024) {
        l += partial[3 * i + 0];
        c += partial[3 * i + 1];
        n += partial[3 * i + 2];
    }
#pragma unroll
    for (int off = 32; off > 0; off >>= 1) {
        l += __shfl_down(l, off);
        c += __shfl_down(c, off);
        n += __shfl_down(n, off);
    }
    const int lane = threadIdx.x & 63;
    const int wid  = threadIdx.x >> 6;
    if (lane == 0) { s[0][wid] = l; s[1][wid] = c; s[2][wid] = n; }
    __syncthreads();
    if (threadIdx.x == 0) {
        float L = 0.0f, C = 0.0f, N = 0.0f;
#pragma unroll
        for (int i = 0; i < 16; ++i) { L += s[0][i]; C += s[1][i]; N += s[2][i]; }
        float np  = fmaxf(1.0f, N);
        float inv = 1.0f / np;
        out[0] = (L + C) * inv;
        out[1] = L * inv;
        out[2] = C * inv;
    }
}

}  // namespace

extern "C" void kernel_launch(void* const* d_in, const int* in_sizes, int n_in,
                              void* d_out, int out_size, void* d_ws, size_t ws_size,
                              hipStream_t stream) {
    const float* loc_preds = (const float*)d_in[0];
    const float* cls_preds = (const float*)d_in[1];
    const float* iou_boxes = (const float*)d_in[2];
    const float* targets   = (const float*)d_in[3];
    float* out = (float*)d_out;
    float* partial = (float*)d_ws;
    unsigned int* wsu = (unsigned int*)d_ws;

    retina_stream<<<dim3(kSBlocks), kBlock, 0, stream>>>(cls_preds, partial, wsu);
    retina_anchor<<<dim3(kGridX, kB), kBlock, 0, stream>>>(iou_boxes, targets, wsu);
    retina_fix<<<dim3(kFBlocks), kBlock, 0, stream>>>(loc_preds, cls_preds, iou_boxes,
                                                      targets, wsu, partial);
    retina_final<<<1, 1024, 0, stream>>>(partial, out);
}

// Round 9
// 168.651 us; speedup vs baseline: 3.0822x; 3.0822x over previous
//
#include <hip/hip_runtime.h>
#include <math.h>

namespace {

constexpr int   kB     = 16;
constexpr int   kA     = 65536;
constexpr int   kM     = 32;
constexpr int   kC     = 20;
constexpr float kImg   = 600.0f;
constexpr int   kBlock = 256;

// stream geometry
constexpr int kSBlocks       = 2048;
constexpr int kStreamThreads = kSBlocks * kBlock;          // 524,288
constexpr int kTotalF4       = kB * kA * kC / 4;           // 5,242,880
constexpr int kF4PerThread   = kTotalF4 / kStreamThreads;  // 10 (exact)

// anchor geometry: 1 anchor/thread, grid (256, 16) -> 4096 blocks = segments
constexpr int kGridX   = kA / kBlock;                      // 256
constexpr int kNSeg    = kGridX * kB;                      // 4096
constexpr int kSegCap  = kBlock;                           // 256 entries (worst case)

// fix geometry: one wave per segment
constexpr int kFixBlocks = kNSeg / 4;                      // 1024 blocks x 4 waves

// partial slots
constexpr int kNPartial = kSBlocks + kFixBlocks;           // 3072 x 3 floats

// workspace u32 layout (all beyond the partial floats; ws is ~335 MB)
constexpr int kPosCnt = 16384;                             // u32[4096]
constexpr int kIgnCnt = kPosCnt + kNSeg;                   // u32[4096]
constexpr int kPosSeg = 32768;                             // u32[4096*256]
constexpr int kIgnSeg = kPosSeg + kNSeg * kSegCap;         // u32[4096*256]

__device__ __forceinline__ float smooth_l1(float d) {
    float ad = fabsf(d);
    return ad < 1.0f ? 0.5f * d * d : ad - 0.5f;
}

// f0(x) = sigmoid(x)^2 * softplus(x)  (t=0 focal term; t=1 is f0(-x)).
// Single definition shared by stream and corrections -> exact cancellation.
__device__ __forceinline__ float f0s(float x) {
    float u  = __expf(-x);
    float d  = 1.0f + u;
    float s  = __builtin_amdgcn_rcpf(d);       // sigmoid(x)
    float sp = x + __logf(d);                  // softplus(x)
    return s * s * sp;
}

// Lessons ledger:
//  R2: no launch_bounds min-waves arg (",6" -> VGPR cap 40 -> 359 MB spill).
//  R4: role-split INSIDE one kernel fails (shared regalloc -> VGPR-128 cliff).
//  R5/R6: VALU cuts in the fused kernel were neutral (structure-bound).
//  R7: anchor kernel = 55us: exec-masked row bodies run in ~every wave.
//  R8: per-wave atomicAdd to ONE global counter = 371us (VALUBusy 5% --
//      ~120K device-scope same-address atomics serialized across 8 XCDs).
//      This round: per-block private segments, ballot+LDS-prefix compaction,
//      ZERO global atomics; fix kernel = one wave per segment.

// ---- Kernel 1: target-free focal stream over cls_preds ---------------------
__global__ __launch_bounds__(kBlock) void retina_stream(
    const float* __restrict__ cls_preds,
    float* __restrict__ partial)           // slots [0, kSBlocks)
{
    __shared__ float sred[kBlock / 64];

    const float4* cp = (const float4*)cls_preds;
    const int t0 = blockIdx.x * kBlock + threadIdx.x;

    float csum = 0.0f;
#pragma unroll
    for (int i = 0; i < kF4PerThread; ++i) {
        float4 v = cp[t0 + i * kStreamThreads];   // coalesced 1 KiB/instr/wave
        csum += f0s(v.x) + f0s(v.y) + f0s(v.z) + f0s(v.w);
    }

#pragma unroll
    for (int off = 32; off > 0; off >>= 1)
        csum += __shfl_down(csum, off);
    const int lane = threadIdx.x & 63;
    const int wid  = threadIdx.x >> 6;
    if (lane == 0) sred[wid] = csum;
    __syncthreads();
    if (threadIdx.x == 0) {
        float c = 0.0f;
#pragma unroll
        for (int i = 0; i < kBlock / 64; ++i) c += sred[i];
        partial[3 * blockIdx.x + 0] = 0.0f;
        partial[3 * blockIdx.x + 1] = 0.75f * c;
        partial[3 * blockIdx.x + 2] = 0.0f;
    }
}

// ---- Kernel 2: IoU argmax + block-private compaction (no global atomics) ---
__global__ __launch_bounds__(kBlock) void retina_anchor(
    const float* __restrict__ iou_boxes,   // [A, 4] xywh
    const float* __restrict__ targets,     // [B*M, 6]
    unsigned int* __restrict__ wsu)
{
    __shared__ float4   sbox[kM];      // x1, y1, x2+1, y2+1 (pixels)
    __shared__ float    sarea[kM];     // target area (+1 convention)
    __shared__ unsigned swcnt[2][kBlock / 64];   // per-wave pos/ign counts

    const int b = blockIdx.y;
    const int a = blockIdx.x * kBlock + threadIdx.x;
    const int s = b * kGridX + blockIdx.x;       // segment id [0, kNSeg)

    if (threadIdx.x < kM) {
        const float* t = targets + ((size_t)(b * kM + threadIdx.x)) * 6;
        float cx = t[2] * kImg, cy = t[3] * kImg;
        float w  = t[4] * kImg, h  = t[5] * kImg;
        float x1  = cx - w * 0.5f,        y1  = cy - h * 0.5f;
        float x2p = cx + w * 0.5f + 1.0f, y2p = cy + h * 0.5f + 1.0f;
        sbox[threadIdx.x]  = make_float4(x1, y1, x2p, y2p);
        sarea[threadIdx.x] = (x2p - x1) * (y2p - y1);
    }

    const float4 an = *(const float4*)(iou_boxes + (size_t)a * 4);

    __syncthreads();

    const float ax1  = an.x - an.z * 0.5f;
    const float ay1  = an.y - an.w * 0.5f;
    const float ax2p = an.x + an.z * 0.5f + 1.0f;
    const float ay2p = an.y + an.w * 0.5f + 1.0f;
    const float aarea = (ax2p - ax1) * (ay2p - ay1);

    float best = -1.0f;
    int   mid  = 0;
#pragma unroll
    for (int m = 0; m < kM; ++m) {
        float4 q = sbox[m];
        float lx = fmaxf(ax1,  q.x);
        float ly = fmaxf(ay1,  q.y);
        float rx = fminf(ax2p, q.z);
        float ry = fminf(ay2p, q.w);
        float w  = fmaxf(rx - lx, 0.0f);
        float h  = fmaxf(ry - ly, 0.0f);
        float inter = w * h;
        float uni   = aarea + sarea[m] - inter;
        float iou   = inter * __builtin_amdgcn_rcpf(uni);
        if (iou > best) { best = iou; mid = m; }
    }

    const bool pos = best >= 0.5f;
    const bool ign = (best > 0.4f) && !pos;
    const int  lane = threadIdx.x & 63;
    const int  wid  = threadIdx.x >> 6;
    const unsigned g = (unsigned)(b * kA + a);            // < 2^20

    const unsigned long long pm = __ballot(pos);
    const unsigned long long im = __ballot(ign);
    if (lane == 0) {
        swcnt[0][wid] = (unsigned)__popcll(pm);
        swcnt[1][wid] = (unsigned)__popcll(im);
    }
    __syncthreads();

    // deterministic in-block (anchor-ordered) offsets: prefix over prior waves
    unsigned pbase = 0, ibase = 0;
    for (int w = 0; w < wid; ++w) { pbase += swcnt[0][w]; ibase += swcnt[1][w]; }
    const unsigned long long below = (1ull << lane) - 1ull;
    if (pos) {
        unsigned off = pbase + (unsigned)__popcll(pm & below);
        wsu[kPosSeg + (unsigned)s * kSegCap + off] = (g << 5) | (unsigned)mid;
    }
    if (ign) {
        unsigned off = ibase + (unsigned)__popcll(im & below);
        wsu[kIgnSeg + (unsigned)s * kSegCap + off] = g;
    }
    if (threadIdx.x == 0) {
        unsigned tp = 0, ti = 0;
#pragma unroll
        for (int w = 0; w < kBlock / 64; ++w) { tp += swcnt[0][w]; ti += swcnt[1][w]; }
        wsu[kPosCnt + s] = tp;
        wsu[kIgnCnt + s] = ti;
    }
}

// ---- Kernel 3: one wave per segment; lanes parallelize over entries --------
__global__ __launch_bounds__(kBlock) void retina_fix(
    const float* __restrict__ loc_preds,
    const float* __restrict__ cls_preds,
    const float* __restrict__ iou_boxes,
    const float* __restrict__ targets,
    const unsigned int* __restrict__ wsu,
    float* __restrict__ partial)           // slots [kSBlocks, kSBlocks+kFixBlocks)
{
    __shared__ float sred[3][kBlock / 64];

    const int lane = threadIdx.x & 63;
    const int wid  = threadIdx.x >> 6;
    const int s    = blockIdx.x * (kBlock / 64) + wid;   // segment [0, kNSeg)

    const unsigned pcnt = wsu[kPosCnt + s];
    const unsigned icnt = wsu[kIgnCnt + s];

    float loc_sum = 0.0f, cls_sum = 0.0f, npos = 0.0f;
    if (lane == 0) npos = (float)pcnt;

    for (unsigned i = lane; i < pcnt; i += 64) {
        const unsigned e = wsu[kPosSeg + (unsigned)s * kSegCap + i];  // coalesced
        const unsigned g = e >> 5;
        const int mid = (int)(e & 31u);
        const int b = (int)(g >> 16);
        const int a = (int)(g & 65535u);
        const float4 an = *(const float4*)(iou_boxes + (size_t)a * 4);
        const float* t = targets + ((size_t)(b * kM + mid)) * 6;
        const float cx = t[2] * kImg, cy = t[3] * kImg;
        const float w  = t[4] * kImg, h  = t[5] * kImg;
        const float4 lp = *(const float4*)(loc_preds + (size_t)g * 4);
        float ltx = (cx - an.x) * __builtin_amdgcn_rcpf(an.z);
        float lty = (cy - an.y) * __builtin_amdgcn_rcpf(an.w);
        float ltw = __logf(w * __builtin_amdgcn_rcpf(an.z));
        float lth = __logf(h * __builtin_amdgcn_rcpf(an.w));
        loc_sum += smooth_l1(lp.x - ltx) + smooth_l1(lp.y - lty) +
                   smooth_l1(lp.z - ltw) + smooth_l1(lp.w - lth);
        const int label = (int)t[1];
        const float x = cls_preds[(size_t)g * kC + label];
        cls_sum += 0.25f * f0s(-x) - 0.75f * f0s(x);
    }

    for (unsigned i = lane; i < icnt; i += 64) {
        const unsigned g = wsu[kIgnSeg + (unsigned)s * kSegCap + i];  // coalesced
        const float* rp = cls_preds + (size_t)g * kC;
        const float4 r0 = *(const float4*)(rp + 0);
        const float4 r1 = *(const float4*)(rp + 4);
        const float4 r2 = *(const float4*)(rp + 8);
        const float4 r3 = *(const float4*)(rp + 12);
        const float4 r4 = *(const float4*)(rp + 16);
        float sv =
            f0s(r0.x) + f0s(r0.y) + f0s(r0.z) + f0s(r0.w) +
            f0s(r1.x) + f0s(r1.y) + f0s(r1.z) + f0s(r1.w) +
            f0s(r2.x) + f0s(r2.y) + f0s(r2.z) + f0s(r2.w) +
            f0s(r3.x) + f0s(r3.y) + f0s(r3.z) + f0s(r3.w) +
            f0s(r4.x) + f0s(r4.y) + f0s(r4.z) + f0s(r4.w);
        cls_sum -= 0.75f * sv;
    }

#pragma unroll
    for (int off = 32; off > 0; off >>= 1) {
        loc_sum += __shfl_down(loc_sum, off);
        cls_sum += __shfl_down(cls_sum, off);
        npos    += __shfl_down(npos, off);
    }
    if (lane == 0) {
        sred[0][wid] = loc_sum;
        sred[1][wid] = cls_sum;
        sred[2][wid] = npos;
    }
    __syncthreads();
    if (threadIdx.x == 0) {
        float l = 0.0f, c = 0.0f, n = 0.0f;
#pragma unroll
        for (int i = 0; i < kBlock / 64; ++i) {
            l += sred[0][i]; c += sred[1][i]; n += sred[2][i];
        }
        const int slot = kSBlocks + blockIdx.x;
        partial[3 * slot + 0] = l;
        partial[3 * slot + 1] = c;
        partial[3 * slot + 2] = n;
    }
}

__global__ __launch_bounds__(1024) void retina_final(
    const float* __restrict__ partial, float* __restrict__ out)
{
    __shared__ float s[3][16];
    float l = 0.0f, c = 0.0f, n = 0.0f;
    for (int i = threadIdx.x; i < kNPartial; i += 1024) {
        l += partial[3 * i + 0];
        c += partial[3 * i + 1];
        n += partial[3 * i + 2];
    }
#pragma unroll
    for (int off = 32; off > 0; off >>= 1) {
        l += __shfl_down(l, off);
        c += __shfl_down(c, off);
        n += __shfl_down(n, off);
    }
    const int lane = threadIdx.x & 63;
    const int wid  = threadIdx.x >> 6;
    if (lane == 0) { s[0][wid] = l; s[1][wid] = c; s[2][wid] = n; }
    __syncthreads();
    if (threadIdx.x == 0) {
        float L = 0.0f, C = 0.0f, N = 0.0f;
#pragma unroll
        for (int i = 0; i < 16; ++i) { L += s[0][i]; C += s[1][i]; N += s[2][i]; }
        float np  = fmaxf(1.0f, N);
        float inv = 1.0f / np;
        out[0] = (L + C) * inv;
        out[1] = L * inv;
        out[2] = C * inv;
    }
}

}  // namespace

extern "C" void kernel_launch(void* const* d_in, const int* in_sizes, int n_in,
                              void* d_out, int out_size, void* d_ws, size_t ws_size,
                              hipStream_t stream) {
    const float* loc_preds = (const float*)d_in[0];
    const float* cls_preds = (const float*)d_in[1];
    const float* iou_boxes = (const float*)d_in[2];
    const float* targets   = (const float*)d_in[3];
    float* out = (float*)d_out;
    float* partial = (float*)d_ws;
    unsigned int* wsu = (unsigned int*)d_ws;

    retina_stream<<<dim3(kSBlocks), kBlock, 0, stream>>>(cls_preds, partial);
    retina_anchor<<<dim3(kGridX, kB), kBlock, 0, stream>>>(iou_boxes, targets, wsu);
    retina_fix<<<dim3(kFixBlocks), kBlock, 0, stream>>>(loc_preds, cls_preds, iou_boxes,
                                                        targets, wsu, partial);
    retina_final<<<1, 1024, 0, stream>>>(partial, out);
}

// Round 10
// 144.194 us; speedup vs baseline: 3.6050x; 1.1696x over previous
//
#include <hip/hip_runtime.h>
#include <math.h>

namespace {

constexpr int   kB     = 16;
constexpr int   kA     = 65536;
constexpr int   kM     = 32;
constexpr int   kC     = 20;
constexpr float kImg   = 600.0f;
constexpr int   kBlock = 256;

constexpr int kAnchPerThread = 4;
constexpr int kAnchPerBlock  = kBlock * kAnchPerThread;  // 1024
constexpr int kGridX         = kA / kAnchPerBlock;       // 64
constexpr int kNBlocks       = kGridX * kB;              // 1024 (ws: 1024*3 floats)

__device__ __forceinline__ float smooth_l1(float d) {
    float ad = fabsf(d);
    return ad < 1.0f ? 0.5f * d * d : ad - 0.5f;
}

// f0(x) = sigmoid(x)^2 * softplus(x)  (t=0 focal term; t=1 is f0(-x)).
// Single definition everywhere -> stream/correction terms cancel exactly.
__device__ __forceinline__ float f0s(float x) {
    float u  = __expf(-x);
    float d  = 1.0f + u;
    float s  = __builtin_amdgcn_rcpf(d);       // sigmoid(x)
    float sp = x + __logf(d);                  // softplus(x)
    return s * s * sp;
}

// Lessons ledger:
//  R2: no launch_bounds min-waves arg (",6" -> VGPR cap 40 -> 359 MB spill).
//  R4: even/odd role split in one kernel -> shared-regalloc VGPR cliff.
//  R7: exec-masked row bodies running in ~every wave = 55us anchor kernel.
//  R8: same-address global atomics = 371us. R9: atomic-free 3-kernel split
//      works but launch gaps + LDS-pipe cost keep it at ~168us total.
//  KEY ACCOUNTING (R9): IoU loop = 2 LDS reads/m-iter/thread = ~15us of
//      LDS-pipe time at 1 anchor/thread. THIS round: 4 anchors/thread share
//      each sbox/sarea read (LDS/4), fused single main kernel (2 launches),
//      rows software-pipelined under IoU/stream compute.
__global__ __launch_bounds__(kBlock) void retina_main(
    const float* __restrict__ loc_preds,   // [B, A, 4]
    const float* __restrict__ cls_preds,   // [B, A, C]
    const float* __restrict__ iou_boxes,   // [A, 4] xywh
    const float* __restrict__ targets,     // [B*M, 6]
    float* __restrict__ partial)           // [kNBlocks][3]
{
    __shared__ float4 sbox[kM];    // x1, y1, x2+1, y2+1 (pixels)
    __shared__ float4 sxywh[kM];   // cx, cy, w, h (pixels)
    __shared__ float  sarea[kM];   // target area (+1 convention)
    __shared__ int    slab[kM];
    __shared__ float  sred[3][kBlock / 64];

    const int b   = blockIdx.y;
    const int ab  = blockIdx.x * kAnchPerBlock;
    const int tid = threadIdx.x;
    const int a0  = ab + tid;                 // thread's anchors: a0 + k*256

    if (tid < kM) {
        const float* t = targets + ((size_t)(b * kM + tid)) * 6;
        float cx = t[2] * kImg, cy = t[3] * kImg;
        float w  = t[4] * kImg, h  = t[5] * kImg;
        float x1  = cx - w * 0.5f,        y1  = cy - h * 0.5f;
        float x2p = cx + w * 0.5f + 1.0f, y2p = cy + h * 0.5f + 1.0f;
        sbox[tid]  = make_float4(x1, y1, x2p, y2p);
        sxywh[tid] = make_float4(cx, cy, w, h);
        sarea[tid] = (x2p - x1) * (y2p - y1);
        slab[tid]  = (int)t[1];
    }

    // Issue global loads BEFORE the barrier: 4 anchor rows + row 0 of cls.
    const float4 an0 = *(const float4*)(iou_boxes + (size_t)(a0 + 0 * kBlock) * 4);
    const float4 an1 = *(const float4*)(iou_boxes + (size_t)(a0 + 1 * kBlock) * 4);
    const float4 an2 = *(const float4*)(iou_boxes + (size_t)(a0 + 2 * kBlock) * 4);
    const float4 an3 = *(const float4*)(iou_boxes + (size_t)(a0 + 3 * kBlock) * 4);

    const float* rp = cls_preds + ((size_t)b * kA + a0) * kC;   // anchor a0's row
    float4 r0 = *(const float4*)(rp + 0);
    float4 r1 = *(const float4*)(rp + 4);
    float4 r2 = *(const float4*)(rp + 8);
    float4 r3 = *(const float4*)(rp + 12);
    float4 r4 = *(const float4*)(rp + 16);

    __syncthreads();

    // Derived per-anchor constants (anchor regs dead after this; pos branch reloads).
#define DERIVE(K, AN) \
    const float x1_##K = AN.x - AN.z * 0.5f; \
    const float y1_##K = AN.y - AN.w * 0.5f; \
    const float x2_##K = AN.x + AN.z * 0.5f + 1.0f; \
    const float y2_##K = AN.y + AN.w * 0.5f + 1.0f; \
    const float ar_##K = (x2_##K - x1_##K) * (y2_##K - y1_##K);
    DERIVE(0, an0) DERIVE(1, an1) DERIVE(2, an2) DERIVE(3, an3)
#undef DERIVE

    float bs0 = -1.0f, bs1 = -1.0f, bs2 = -1.0f, bs3 = -1.0f;
    int   m0 = 0, m1 = 0, m2 = 0, m3 = 0;

    // ---- IoU argmax: ONE sbox/sarea read serves FOUR anchors ----
#pragma unroll 8
    for (int m = 0; m < kM; ++m) {
        const float4 q  = sbox[m];
        const float  ar = sarea[m];
#define IOU(K) { \
        float lx = fmaxf(x1_##K, q.x); \
        float ly = fmaxf(y1_##K, q.y); \
        float rx = fminf(x2_##K, q.z); \
        float ry = fminf(y2_##K, q.w); \
        float w  = fmaxf(rx - lx, 0.0f); \
        float h  = fmaxf(ry - ly, 0.0f); \
        float inter = w * h; \
        float uni   = ar_##K + ar - inter; \
        float iou   = inter * __builtin_amdgcn_rcpf(uni); \
        if (iou > bs##K) { bs##K = iou; m##K = m; } }
        IOU(0) IOU(1) IOU(2) IOU(3)
#undef IOU
    }

    const bool pos0 = bs0 >= 0.5f, ign0 = (bs0 > 0.4f) && !pos0;
    const bool pos1 = bs1 >= 0.5f, ign1 = (bs1 > 0.4f) && !pos1;
    const bool pos2 = bs2 >= 0.5f, ign2 = (bs2 > 0.4f) && !pos2;
    const bool pos3 = bs3 >= 0.5f, ign3 = (bs3 > 0.4f) && !pos3;

    float loc_sum = 0.0f, cls_sum = 0.0f, npos = 0.0f;

    // pos/ign handling for anchor k (rare; exec-masked). Reloads what it needs.
#define POSFIX(K) \
    if (pos##K) { \
        npos += 1.0f; \
        const int ak = a0 + K * kBlock; \
        const float4 an = *(const float4*)(iou_boxes + (size_t)ak * 4); \
        const float4 lp = *(const float4*)(loc_preds + ((size_t)b * kA + ak) * 4); \
        const float4 mb = sxywh[m##K]; \
        float ltx = (mb.x - an.x) * __builtin_amdgcn_rcpf(an.z); \
        float lty = (mb.y - an.y) * __builtin_amdgcn_rcpf(an.w); \
        float ltw = __logf(mb.z * __builtin_amdgcn_rcpf(an.z)); \
        float lth = __logf(mb.w * __builtin_amdgcn_rcpf(an.w)); \
        loc_sum += smooth_l1(lp.x - ltx) + smooth_l1(lp.y - lty) + \
                   smooth_l1(lp.z - ltw) + smooth_l1(lp.w - lth); \
        const float xc = (rp + (size_t)K * kBlock * kC)[slab[m##K]]; \
        cls_sum += 0.25f * f0s(-xc) - 0.75f * f0s(xc); \
    }

#define S20(A0,A1,A2,A3,A4) \
    (f0s(A0.x) + f0s(A0.y) + f0s(A0.z) + f0s(A0.w) + \
     f0s(A1.x) + f0s(A1.y) + f0s(A1.z) + f0s(A1.w) + \
     f0s(A2.x) + f0s(A2.y) + f0s(A2.z) + f0s(A2.w) + \
     f0s(A3.x) + f0s(A3.y) + f0s(A3.z) + f0s(A3.w) + \
     f0s(A4.x) + f0s(A4.y) + f0s(A4.z) + f0s(A4.w))

#define ROWLOAD(D0,D1,D2,D3,D4, KK) { \
    const float* p_ = rp + (size_t)(KK) * kBlock * kC; \
    D0 = *(const float4*)(p_ + 0); \
    D1 = *(const float4*)(p_ + 4); \
    D2 = *(const float4*)(p_ + 8); \
    D3 = *(const float4*)(p_ + 12); \
    D4 = *(const float4*)(p_ + 16); }

    float4 n0, n1, n2, n3, n4;

    // k = 0: prefetch row 1, stream row 0
    ROWLOAD(n0, n1, n2, n3, n4, 1)
    cls_sum += (ign0 ? 0.0f : 0.75f) * S20(r0, r1, r2, r3, r4);
    POSFIX(0)
    r0 = n0; r1 = n1; r2 = n2; r3 = n3; r4 = n4;

    // k = 1: prefetch row 2, stream row 1
    ROWLOAD(n0, n1, n2, n3, n4, 2)
    cls_sum += (ign1 ? 0.0f : 0.75f) * S20(r0, r1, r2, r3, r4);
    POSFIX(1)
    r0 = n0; r1 = n1; r2 = n2; r3 = n3; r4 = n4;

    // k = 2: prefetch row 3, stream row 2
    ROWLOAD(n0, n1, n2, n3, n4, 3)
    cls_sum += (ign2 ? 0.0f : 0.75f) * S20(r0, r1, r2, r3, r4);
    POSFIX(2)
    r0 = n0; r1 = n1; r2 = n2; r3 = n3; r4 = n4;

    // k = 3: stream row 3
    cls_sum += (ign3 ? 0.0f : 0.75f) * S20(r0, r1, r2, r3, r4);
    POSFIX(3)

#undef POSFIX
#undef S20
#undef ROWLOAD

    // ---- Reduce: wave shuffle -> LDS -> per-block partial (no atomics) ----
#pragma unroll
    for (int off = 32; off > 0; off >>= 1) {
        loc_sum += __shfl_down(loc_sum, off);
        cls_sum += __shfl_down(cls_sum, off);
        npos    += __shfl_down(npos, off);
    }
    const int lane = tid & 63;
    const int wid  = tid >> 6;
    if (lane == 0) {
        sred[0][wid] = loc_sum;
        sred[1][wid] = cls_sum;
        sred[2][wid] = npos;
    }
    __syncthreads();
    if (tid == 0) {
        float l = 0.0f, c = 0.0f, n = 0.0f;
#pragma unroll
        for (int i = 0; i < kBlock / 64; ++i) {
            l += sred[0][i]; c += sred[1][i]; n += sred[2][i];
        }
        const int bid = blockIdx.y * gridDim.x + blockIdx.x;
        partial[3 * bid + 0] = l;
        partial[3 * bid + 1] = c;
        partial[3 * bid + 2] = n;
    }
}

__global__ __launch_bounds__(1024) void retina_final(
    const float* __restrict__ partial, float* __restrict__ out)
{
    __shared__ float s[3][16];
    float l = 0.0f, c = 0.0f, n = 0.0f;
    for (int i = threadIdx.x; i < kNBlocks; i += 1024) {
        l += partial[3 * i + 0];
        c += partial[3 * i + 1];
        n += partial[3 * i + 2];
    }
#pragma unroll
    for (int off = 32; off > 0; off >>= 1) {
        l += __shfl_down(l, off);
        c += __shfl_down(c, off);
        n += __shfl_down(n, off);
    }
    const int lane = threadIdx.x & 63;
    const int wid  = threadIdx.x >> 6;
    if (lane == 0) { s[0][wid] = l; s[1][wid] = c; s[2][wid] = n; }
    __syncthreads();
    if (threadIdx.x == 0) {
        float L = 0.0f, C = 0.0f, N = 0.0f;
#pragma unroll
        for (int i = 0; i < 16; ++i) { L += s[0][i]; C += s[1][i]; N += s[2][i]; }
        float np  = fmaxf(1.0f, N);
        float inv = 1.0f / np;
        out[0] = (L + C) * inv;
        out[1] = L * inv;
        out[2] = C * inv;
    }
}

}  // namespace

extern "C" void kernel_launch(void* const* d_in, const int* in_sizes, int n_in,
                              void* d_out, int out_size, void* d_ws, size_t ws_size,
                              hipStream_t stream) {
    const float* loc_preds = (const float*)d_in[0];
    const float* cls_preds = (const float*)d_in[1];
    const float* iou_boxes = (const float*)d_in[2];
    const float* targets   = (const float*)d_in[3];
    float* out     = (float*)d_out;
    float* partial = (float*)d_ws;   // 1024*3 floats, fully overwritten each call

    dim3 grid(kGridX, kB);
    retina_main<<<grid, kBlock, 0, stream>>>(loc_preds, cls_preds, iou_boxes, targets, partial);
    retina_final<<<1, 1024, 0, stream>>>(partial, out);
}